// Round 5
// baseline (1079.515 us; speedup 1.0000x reference)
//
#include <hip/hip_runtime.h>
#include <stdint.h>

// RotEncoderMLP via Z4-spectral (DFT) decomposition of the C4 group convs.
//   x^[0]=x0+x1+x2+x3, x^[2]=x0-x1+x2-x3, x^[1]=ur+i*ui (ur=x0-x2, ui=x3-x1)
//   y^[w] = conj(W^[w]) . x^[w];  y[g] = (1/4)[y^0 + (-1)^g y^2 + 2 Re(y^1 i^g)]
// MACs: 16*HID^2 -> 6*HID^2.
// R7: 256x256 8-phase pipelined GEMM (m201 template: T2+T3+T4+T5).
// R8: balanced panels. R9: persistent-snake LPT + fused L3 (duty 60->85%).
// R10: P8-stage slack fix (282us/chunk, MfmaUtil 39.7). Merged path never ran:
//      ws < 399 MB. Occupancy is register-capped at 2 waves/SIMD (acc=128).
// R11: make the merge FIT in R9's proven 315 MB budget by using d_out as the
//      high half of full-rows h1s (dead until out_ep fully overwrites it).
//      ONE 1280-tile L2 dispatch; removes a dispatch ramp + the serialized
//      LN(c0)/L1(c1) between chunks. Tail prefetches wrap k->0 (no overshoot
//      past d_out; load COUNT unchanged -> vmcnt ledger intact). Band-major
//      work order (nt-fastest in 8-mt bands) shrinks the live A window.

#define HID 2048
#define MROWS 10240

typedef float floatx4 __attribute__((ext_vector_type(4)));
typedef __bf16 bf16x8 __attribute__((ext_vector_type(8)));

__device__ __forceinline__ unsigned short f2bf(float f) {
  union { float f; unsigned int u; } v; v.f = f;
  unsigned int r = v.u + 0x7fffu + ((v.u >> 16) & 1u);  // RNE
  return (unsigned short)(r >> 16);
}
__device__ __forceinline__ float bf2f(unsigned short s) {
  union { unsigned int u; float f; } v; v.u = ((unsigned int)s) << 16;
  return v.f;
}

// ---------- spectral weight transform: w (4,NO,2048) f32 -> W0s, W2s (NO x 2048 bf16),
// Bc (2*NO x 4096 bf16) = [[Vr, -Vi],[Vi, Vr]] ----------
template <int NO>
__global__ __launch_bounds__(256) void wtrans_kernel(const float* __restrict__ w,
                                                     unsigned short* __restrict__ W0s,
                                                     unsigned short* __restrict__ W2s,
                                                     unsigned short* __restrict__ Bc) {
  int idx = blockIdx.x * 256 + threadIdx.x;       // i * 512 + j4
  int i = idx >> 9, j4 = idx & 511;
  const float4* wp = (const float4*)w;
  float4 w0 = wp[0 * NO * 512 + i * 512 + j4];
  float4 w1 = wp[1 * NO * 512 + i * 512 + j4];
  float4 w2 = wp[2 * NO * 512 + i * 512 + j4];
  float4 w3 = wp[3 * NO * 512 + i * 512 + j4];
  ushort4 s0, s2, vr, vi, nvi;
#define DO(c)                                        \
  s0.c = f2bf(w0.c + w1.c + w2.c + w3.c);            \
  s2.c = f2bf(w0.c - w1.c + w2.c - w3.c);            \
  vr.c = f2bf(w0.c - w2.c);                          \
  vi.c = f2bf(w1.c - w3.c);                          \
  nvi.c = f2bf(-(w1.c - w3.c));
  DO(x) DO(y) DO(z) DO(w)
#undef DO
  ((ushort4*)W0s)[i * 512 + j4] = s0;
  ((ushort4*)W2s)[i * 512 + j4] = s2;
  ((ushort4*)Bc)[i * 1024 + j4] = vr;            // row i:    [Vr | -Vi]
  ((ushort4*)Bc)[i * 1024 + 512 + j4] = nvi;
  ((ushort4*)Bc)[(NO + i) * 1024 + j4] = vi;     // row NO+i: [Vi |  Vr]
  ((ushort4*)Bc)[(NO + i) * 1024 + 512 + j4] = vr;
}

// ---------- orbit-stack + layer1 + relu + forward-DFT -> h1 bf16 (rows x 8192: [u0|u2|ur|ui]) ----------
// Output rows (chunk-local orow) split: orow < msplit -> hlo, else hhi.
__global__ __launch_bounds__(256) void layer1_kernel(const float* __restrict__ ins,
                                                     const float* __restrict__ w1,
                                                     const float* __restrict__ b1,
                                                     unsigned short* __restrict__ hlo,
                                                     unsigned short* __restrict__ hhi,
                                                     int msplit, int row0) {
  __shared__ float orbs[32][28];
  int t = threadIdx.x;
  int b0 = blockIdx.x * 32;            // chunk-local
  int i = blockIdx.y * 256 + t;
  if (t < 32) {
    const float* x = ins + (size_t)(row0 + b0 + t) * 25;
    float v[25];
#pragma unroll
    for (int p = 0; p < 25; ++p) v[p] = x[p];
    float* o = orbs[t];
    o[0] = v[12]; o[7] = v[12]; o[14] = v[12]; o[21] = v[12];
#pragma unroll
    for (int r = 0; r < 2; ++r)
#pragma unroll
      for (int c = 0; c < 3; ++c) {
        int m = 1 + r * 3 + c;
        o[m]      = v[r * 5 + c];
        o[7 + m]  = v[c * 5 + (4 - r)];
        o[14 + m] = v[(4 - r) * 5 + (4 - c)];
        o[21 + m] = v[(4 - c) * 5 + r];
      }
  }
  __syncthreads();
  float w[4][7];
#pragma unroll
  for (int r = 0; r < 4; ++r)
#pragma unroll
    for (int j = 0; j < 7; ++j) w[r][j] = w1[(r * HID + i) * 7 + j];
  float bias = b1[i];
  for (int s = 0; s < 32; ++s) {
    float a[4] = {bias, bias, bias, bias};
#pragma unroll
    for (int hh = 0; hh < 4; ++hh)
#pragma unroll
      for (int j = 0; j < 7; ++j) {
        float ov = orbs[s][hh * 7 + j];
#pragma unroll
        for (int g = 0; g < 4; ++g) a[g] += w[(hh - g) & 3][j] * ov;
      }
    float h0 = fmaxf(a[0], 0.f), h1 = fmaxf(a[1], 0.f);
    float h2 = fmaxf(a[2], 0.f), h3 = fmaxf(a[3], 0.f);
    int orow = b0 + s;
    unsigned short* hp = (orow < msplit) ? hlo + (size_t)orow * 8192
                                         : hhi + (size_t)(orow - msplit) * 8192;
    hp[i]        = f2bf(h0 + h1 + h2 + h3);  // u0
    hp[2048 + i] = f2bf(h0 - h1 + h2 - h3);  // u2
    hp[4096 + i] = f2bf(h0 - h2);            // ur
    hp[6144 + i] = f2bf(h3 - h1);            // ui
  }
}

// ---------- persistent 256x256 8-phase pipelined bf16 MFMA GEMM ----------
// Work list (LPT, band-major): tiles [0,NTL) = long-K (CL cols at nt=s2..),
// [NTL,NT) = short-K (CS cols at nt=0..). Within a region: bands of BH m-tiles,
// nt fastest (keeps the concurrent A window to ~2 bands). G blocks snake:
// pass p -> tile p*G+b (even) / (p+1)*G-1-b (odd).
// A rows split: m0 < MS -> Alo else Ahi (R11: high half may live in d_out).
// n-tile routing: nt<s1: B0,K=2048,aoff=0; nt<s2: B1,K=2048,aoff=2048; else B2,K=4096,aoff=4096.
// Output: bf16 to Cb (if non-null) else f32 to Cf.
// LDS: row remap (half-tile = 2 contiguous 64-row global_load_lds sweeps);
// chunk swizzle ch ^= (lrow&7), source pre-swizzled, read ch = c ^ (lane15&7).
// Stage ring: P2:A0mh0 P3:B0nh0 P4:B0nh1 P5:A0mh1 P6:A1mh0 P7:B1nh0
// P8:B1nh1+A1mh1; counted vmcnt(6) at P4/P8 only. Tail stages wrap k->0
// (garbage, never consumed; keeps load counts == ledger, no OOB reads).

__global__ __launch_bounds__(512, 2) void gemm_spec(const unsigned short* __restrict__ Alo,
                                                    const unsigned short* __restrict__ Ahi,
                                                    int MS,
                                                    const unsigned short* __restrict__ B0,
                                                    const unsigned short* __restrict__ B1,
                                                    const unsigned short* __restrict__ B2,
                                                    float* __restrict__ Cf,
                                                    unsigned short* __restrict__ Cb,
                                                    int s1, int s2, int N0, int ldc,
                                                    int NT, int NTL, int MTN,
                                                    int CL, int CS) {
  __shared__ __align__(16) unsigned short As[2][16384];
  __shared__ __align__(16) unsigned short Bs[2][16384];
  int tid = threadIdx.x;
  int wave = tid >> 6, lane = tid & 63;
  int lane15 = lane & 15, lane4 = lane >> 4, l7 = lane15 & 7;
  int wm = wave >> 2, wn = wave & 3;
  int wm64 = wm << 6, wn32 = wn << 5;

  int srow = tid >> 3;                               // 0..63 within a sweep
  int scol = ((tid & 7) ^ ((tid >> 3) & 7)) << 3;    // pre-swizzled source chunk
  int bs64 = (srow >> 5) << 6;                       // 0 or 64 (wave-uniform)
  int BH = (MTN % 8 == 0) ? 8 : ((MTN % 4 == 0) ? 4 : 1);

#define STA(buf, mh, kk)                                                                              \
  __builtin_amdgcn_global_load_lds(                                                                   \
      (const __attribute__((address_space(1))) void*)(Agb + (size_t)((mh) * 64) * 8192 + (kk)),       \
      (__attribute__((address_space(3))) void*)((char*)As[buf] + (mh) * 16384 + wave * 1024),         \
      16, 0, 0);                                                                                      \
  __builtin_amdgcn_global_load_lds(                                                                   \
      (const __attribute__((address_space(1))) void*)(Agb + (size_t)((mh) * 64 + 128) * 8192 + (kk)), \
      (__attribute__((address_space(3))) void*)((char*)As[buf] + (mh) * 16384 + 8192 + wave * 1024),  \
      16, 0, 0)

#define STB(buf, nh, kk)                                                                              \
  __builtin_amdgcn_global_load_lds(                                                                   \
      (const __attribute__((address_space(1))) void*)(Bgb + (size_t)(bs64 + (nh) * 32) * ldb + (kk)), \
      (__attribute__((address_space(3))) void*)((char*)Bs[buf] + (nh) * 16384 + wave * 1024),         \
      16, 0, 0);                                                                                      \
  __builtin_amdgcn_global_load_lds(                                                                   \
      (const __attribute__((address_space(1))) void*)(Bgb + (size_t)(bs64 + 128 + (nh) * 32) * ldb + (kk)), \
      (__attribute__((address_space(3))) void*)((char*)Bs[buf] + (nh) * 16384 + 8192 + wave * 1024),  \
      16, 0, 0)

#define RAF(buf, mh)                                                                                  \
  _Pragma("unroll") for (int mi_ = 0; mi_ < 4; ++mi_)                                                 \
  _Pragma("unroll") for (int ks_ = 0; ks_ < 2; ++ks_)                                                 \
      af[mi_][ks_] = *(const bf16x8*)((const char*)As[buf] +                                          \
          (((mh) * 128 + wm64 + mi_ * 16 + lane15) << 7) + (((ks_ * 4 + lane4) ^ l7) << 4))

#define RBF(dst, buf, nh)                                                                             \
  _Pragma("unroll") for (int ni_ = 0; ni_ < 2; ++ni_)                                                 \
  _Pragma("unroll") for (int ks_ = 0; ks_ < 2; ++ks_)                                                 \
      dst[ni_][ks_] = *(const bf16x8*)((const char*)Bs[buf] +                                         \
          (((nh) * 128 + wn32 + ni_ * 16 + lane15) << 7) + (((ks_ * 4 + lane4) ^ l7) << 4))

#define MM(mh, nh, bF)                                                                                \
  _Pragma("unroll") for (int mi_ = 0; mi_ < 4; ++mi_)                                                 \
  _Pragma("unroll") for (int ni_ = 0; ni_ < 2; ++ni_)                                                 \
  _Pragma("unroll") for (int ks_ = 0; ks_ < 2; ++ks_)                                                 \
      acc[(mh) * 4 + mi_][(nh) * 2 + ni_] = __builtin_amdgcn_mfma_f32_16x16x32_bf16(                  \
          af[mi_][ks_], bF[ni_][ks_], acc[(mh) * 4 + mi_][(nh) * 2 + ni_], 0, 0, 0)

#define BAR() __builtin_amdgcn_s_barrier()
#define LGKM0() asm volatile("s_waitcnt lgkmcnt(0)" ::: "memory")
#define LGKM8() asm volatile("s_waitcnt lgkmcnt(8)" ::: "memory")
#define VM6() asm volatile("s_waitcnt vmcnt(6)" ::: "memory")
#define VM8() asm volatile("s_waitcnt vmcnt(8)" ::: "memory")

  bf16x8 af[4][2], b0r[2][2], b1r[2][2];
  const floatx4 fz = {0.f, 0.f, 0.f, 0.f};
  floatx4 acc[8][4];

  int G = (int)gridDim.x;
  for (int pass = 0;; ++pass) {
    int base = pass * G;
    if (base >= NT) break;
    int wt = (pass & 1) ? (base + G - 1 - (int)blockIdx.x) : (base + (int)blockIdx.x);
    if (wt >= NT) continue;

    // band-major tile decode
    int mt, nt;
    if (wt < NTL) {
      int per = CL * BH;
      int band = wt / per, r = wt % per;
      nt = s2 + r % CL; mt = band * BH + r / CL;
    } else {
      int j = wt - NTL;
      int per = CS * BH;
      int band = j / per, r = j % per;
      nt = r % CS; mt = band * BH + r / CS;
    }
    int m0 = mt * 256;

    const unsigned short* Bp;
    int K, aoff, coff, nloc;
    if (nt < s1)      { Bp = B0; K = 2048; aoff = 0;    coff = 0;      nloc = nt * 256; }
    else if (nt < s2) { Bp = B1; K = 2048; aoff = 2048; coff = N0;     nloc = (nt - s1) * 256; }
    else              { Bp = B2; K = 4096; aoff = 4096; coff = 2 * N0; nloc = (nt - s2) * 256; }
    int ldb = K;

    const unsigned short* Ab = (m0 < MS) ? (Alo + (size_t)m0 * 8192)
                                         : (Ahi + (size_t)(m0 - MS) * 8192);
    const unsigned short* Agb = Ab + (size_t)srow * 8192 + aoff + scol;
    const unsigned short* Bgb = Bp + (size_t)(nloc + (srow & 31)) * ldb + scol;

#pragma unroll
    for (int a = 0; a < 8; ++a)
#pragma unroll
      for (int b = 0; b < 4; ++b) acc[a][b] = fz;

    // Prologue: T0 (buf0,k=0) then T1 (buf1,k=64), all 16 loads; vmcnt(8)
    // retires exactly T0's 8 (drains prev epilogue stores first, FIFO).
    STA(0, 0, 0); STB(0, 0, 0); STB(0, 1, 0); STA(0, 1, 0);
    STA(1, 0, 64); STB(1, 0, 64); STB(1, 1, 64); STA(1, 1, 64);
    VM8();
    BAR();

    for (int k0 = 0; k0 < K; k0 += 128) {
      int ka = k0 + 128; if (ka >= K) ka = 0;   // tail wrap: garbage, never
      int kb = k0 + 192; if (kb >= K) kb = 0;   // consumed; count unchanged
      // ---- P1: quad(0,0) of tile A (buf0)
      RAF(0, 0); RBF(b0r, 0, 0);
      LGKM8();
      BAR(); LGKM0();
      __builtin_amdgcn_s_setprio(1); MM(0, 0, b0r); __builtin_amdgcn_s_setprio(0);
      BAR();
      // ---- P2: quad(0,1); stage Ta'.A-mh0 (buf0, freed P1)
      RBF(b1r, 0, 1);
      STA(0, 0, ka);
      BAR(); LGKM0();
      __builtin_amdgcn_s_setprio(1); MM(0, 1, b1r); __builtin_amdgcn_s_setprio(0);
      BAR();
      // ---- P3: quad(1,0); stage Ta'.B-nh0 (freed P1)
      RAF(0, 1);
      STB(0, 0, ka);
      BAR(); LGKM0();
      __builtin_amdgcn_s_setprio(1); MM(1, 0, b0r); __builtin_amdgcn_s_setprio(0);
      BAR();
      // ---- P4: quad(1,1); stage Ta'.B-nh1 (freed P2); counted vmcnt
      // outstanding: prevP7(2)+prevP8(4)+P2..P4(6)=12 -> retire prevP7+prevP8
      STB(0, 1, ka);
      BAR(); LGKM0();
      __builtin_amdgcn_s_setprio(1); MM(1, 1, b1r); __builtin_amdgcn_s_setprio(0);
      VM6();
      BAR();
      // ---- P5: tile B (buf1) quad(0,0); stage Ta'.A-mh1 (freed P3)
      RAF(1, 0); RBF(b0r, 1, 0);
      STA(0, 1, ka);
      LGKM8();
      BAR(); LGKM0();
      __builtin_amdgcn_s_setprio(1); MM(0, 0, b0r); __builtin_amdgcn_s_setprio(0);
      BAR();
      // ---- P6: quad(0,1); stage Tb'.A-mh0 (buf1, freed P5)
      RBF(b1r, 1, 1);
      STA(1, 0, kb);
      BAR(); LGKM0();
      __builtin_amdgcn_s_setprio(1); MM(0, 1, b1r); __builtin_amdgcn_s_setprio(0);
      BAR();
      // ---- P7: quad(1,0); stage Tb'.B-nh0 (freed P5)
      RAF(1, 1);
      STB(1, 0, kb);
      BAR(); LGKM0();
      __builtin_amdgcn_s_setprio(1); MM(1, 0, b0r); __builtin_amdgcn_s_setprio(0);
      BAR();
      // ---- P8: quad(1,1); stage Tb'.B-nh1 (freed P6) + Tb'.A-mh1 (freed P7);
      // counted vmcnt: outstanding P5..P8(10) -> retire P5+P6
      STB(1, 1, kb);
      STA(1, 1, kb);
      BAR(); LGKM0();
      __builtin_amdgcn_s_setprio(1); MM(1, 1, b1r); __builtin_amdgcn_s_setprio(0);
      VM6();
      BAR();
    }
    asm volatile("s_waitcnt vmcnt(0)" ::: "memory");

    // epilogue: C/D layout col=lane&15, row=(lane>>4)*4+r
#pragma unroll
    for (int ni = 0; ni < 4; ++ni) {
      int col = coff + nloc + wn * 64 + (ni >> 1) * 32 + (ni & 1) * 16 + lane15;
#pragma unroll
      for (int mi = 0; mi < 8; ++mi) {
        int row = m0 + wm * 128 + (mi >> 2) * 64 + (mi & 3) * 16 + lane4 * 4;
        if (Cb) {
#pragma unroll
          for (int r = 0; r < 4; ++r)
            Cb[(size_t)(row + r) * ldc + col] = f2bf(acc[mi][ni][r]);
        } else {
#pragma unroll
          for (int r = 0; r < 4; ++r)
            Cf[(size_t)(row + r) * ldc + col] = acc[mi][ni][r];
        }
      }
    }
  }
#undef STA
#undef STB
#undef RAF
#undef RBF
#undef MM
#undef BAR
#undef LGKM0
#undef LGKM8
#undef VM6
#undef VM8
}

// ---------- inverse-DFT (+b2, /4) -> 4x LayerNorm -> relu -> forward-DFT -> out bf16 ----------
// NOTE: may be called with h1s == C2 (in-place): each row is fully register-
// resident between read and write (reads all precede the reduction barrier).
__global__ __launch_bounds__(256) void ln_spec_kernel(const unsigned short* C2,
                                                      const float* __restrict__ b2,
                                                      const float* __restrict__ ln_g,
                                                      const float* __restrict__ ln_b,
                                                      unsigned short* h1s) {
  int t = threadIdx.x;
  size_t base = (size_t)blockIdx.x * 8192;
  const ushort4* p = (const ushort4*)(C2 + base);   // planes: v0|v2|vr|vi (512 ushort4 each)
  const float4* bp2 = (const float4*)b2;
  float4 y[4][2];
  float s[4] = {0, 0, 0, 0}, q[4] = {0, 0, 0, 0};
#pragma unroll
  for (int hl = 0; hl < 2; ++hl) {
    int j = hl * 256 + t;
    ushort4 u0 = p[j], u2 = p[512 + j], ur = p[1024 + j], ui = p[1536 + j];
    float4 bb = bp2[j];
#define DO(c)                                                   \
  {                                                             \
    float v0 = bf2f(u0.c), v2 = bf2f(u2.c);                     \
    float vr = bf2f(ur.c), vi = bf2f(ui.c);                     \
    float e0 = 0.25f * (v0 + v2 + 2.f * vr) + bb.c;             \
    float e1 = 0.25f * (v0 - v2 - 2.f * vi) + bb.c;             \
    float e2 = 0.25f * (v0 + v2 - 2.f * vr) + bb.c;             \
    float e3 = 0.25f * (v0 - v2 + 2.f * vi) + bb.c;             \
    y[0][hl].c = e0; y[1][hl].c = e1; y[2][hl].c = e2; y[3][hl].c = e3; \
    s[0] += e0; q[0] += e0 * e0; s[1] += e1; q[1] += e1 * e1;   \
    s[2] += e2; q[2] += e2 * e2; s[3] += e3; q[3] += e3 * e3;   \
  }
    DO(x) DO(y) DO(z) DO(w)
#undef DO
  }
#pragma unroll
  for (int off = 32; off > 0; off >>= 1)
#pragma unroll
    for (int g = 0; g < 4; ++g) {
      s[g] += __shfl_down(s[g], off, 64);
      q[g] += __shfl_down(q[g], off, 64);
    }
  __shared__ float rs[4][4], rq[4][4];
  int w = t >> 6, l = t & 63;
  if (l == 0)
#pragma unroll
    for (int g = 0; g < 4; ++g) { rs[w][g] = s[g]; rq[w][g] = q[g]; }
  __syncthreads();
  float mean[4], rstd[4];
#pragma unroll
  for (int g = 0; g < 4; ++g) {
    float ss = rs[0][g] + rs[1][g] + rs[2][g] + rs[3][g];
    float qq = rq[0][g] + rq[1][g] + rq[2][g] + rq[3][g];
    mean[g] = ss * (1.f / HID);
    float var = qq * (1.f / HID) - mean[g] * mean[g];
    rstd[g] = rsqrtf(var + 1e-5f);
  }
  const float4* gp = (const float4*)ln_g;
  const float4* lbp = (const float4*)ln_b;
#pragma unroll
  for (int hl = 0; hl < 2; ++hl) {
    int j = hl * 256 + t;
    float4 gg = gp[j], lb = lbp[j];
    ushort4 o[4];
#define DO(c)                                                               \
  {                                                                         \
    float h0 = fmaxf((y[0][hl].c - mean[0]) * rstd[0] * gg.c + lb.c, 0.f);  \
    float h1 = fmaxf((y[1][hl].c - mean[1]) * rstd[1] * gg.c + lb.c, 0.f);  \
    float h2 = fmaxf((y[2][hl].c - mean[2]) * rstd[2] * gg.c + lb.c, 0.f);  \
    float h3 = fmaxf((y[3][hl].c - mean[3]) * rstd[3] * gg.c + lb.c, 0.f);  \
    o[0].c = f2bf(h0 + h1 + h2 + h3);                                       \
    o[1].c = f2bf(h0 - h1 + h2 - h3);                                       \
    o[2].c = f2bf(h0 - h2);                                                 \
    o[3].c = f2bf(h3 - h1);                                                 \
  }
    DO(x) DO(y) DO(z) DO(w)
#undef DO
    size_t ob = (size_t)blockIdx.x * 8192;
#pragma unroll
    for (int pl = 0; pl < 4; ++pl)
      ((ushort4*)(h1s + ob + pl * 2048))[j] = o[pl];
  }
}

// ---------- final inverse-DFT (+b3, /4): Z (rows x 2048 f32 [z0|z2|zr|zi]) -> out ----------
__global__ __launch_bounds__(256) void out_ep_kernel(const float* __restrict__ Z,
                                                     const float* __restrict__ b3,
                                                     float* __restrict__ out) {
  int e = blockIdx.x * 256 + threadIdx.x;
  int row = e >> 9, i = e & 511;
  size_t base = (size_t)row * 2048;
  float z0 = Z[base + i], z2 = Z[base + 512 + i];
  float zr = Z[base + 1024 + i], zi = Z[base + 1536 + i];
  float bv = b3[i];
  out[base + i]        = 0.25f * (z0 + z2 + 2.f * zr) + bv;
  out[base + 512 + i]  = 0.25f * (z0 - z2 - 2.f * zi) + bv;
  out[base + 1024 + i] = 0.25f * (z0 + z2 - 2.f * zr) + bv;
  out[base + 1536 + i] = 0.25f * (z0 - z2 + 2.f * zi) + bv;
}

extern "C" void kernel_launch(void* const* d_in, const int* in_sizes, int n_in,
                              void* d_out, int out_size, void* d_ws, size_t ws_size,
                              hipStream_t stream) {
  const float* ins = (const float*)d_in[0];
  const float* w1  = (const float*)d_in[1];
  const float* b1  = (const float*)d_in[2];
  const float* w2  = (const float*)d_in[3];
  const float* b2  = (const float*)d_in[4];
  const float* w3  = (const float*)d_in[5];
  const float* b3  = (const float*)d_in[6];
  const float* lng = (const float*)d_in[7];
  const float* lnb = (const float*)d_in[8];
  float* out = (float*)d_out;
  char* ws = (char*)d_ws;
  const int BIGMS = 0x40000000;

  // Spectral weights (bf16), persistent at base of ws.
  unsigned short* W0s2 = (unsigned short*)ws;
  unsigned short* W2s2 = W0s2 + 4194304;
  unsigned short* Bc2  = W2s2 + 4194304;
  unsigned short* W0s3 = Bc2 + 16777216;
  unsigned short* W2s3 = W0s3 + 1048576;
  unsigned short* Bc3  = W2s3 + 1048576;
  const size_t WT_BYTES = 62914560ull;
  char* chunk_base = ws + WT_BYTES;

  wtrans_kernel<2048><<<4096, 256, 0, stream>>>(w2, W0s2, W2s2, Bc2);
  wtrans_kernel<512><<<1024, 256, 0, stream>>>(w3, W0s3, W2s3, Bc3);

  const size_t H1L_BYTES = (size_t)5120 * 8192 * 2;     // 84 MB: rows 0..5119 (Z f32 full aliases this)
  const size_t H2_BYTES  = (size_t)MROWS * 8192 * 2;    // 168 MB
  const size_t need_merged = WT_BYTES + H1L_BYTES + H2_BYTES + 4096;  // 315 MB (== R9's budget)

  if (ws_size >= need_merged && (size_t)out_size >= (size_t)5120 * 8192 * 2) {
    // ---- merged path: full-rows h1s split (lo in ws, hi in d_out) ----
    unsigned short* h1lo = (unsigned short*)chunk_base;               // rows 0..5119
    unsigned short* h1hi = (unsigned short*)out;                      // rows 5120..10239 (dead before out_ep)
    float*          Z    = (float*)chunk_base;                        // 10240 x 2048 f32 (alias h1lo; h1s dead by then)
    unsigned short* H2   = (unsigned short*)(chunk_base + H1L_BYTES); // 10240 x 8192 bf16
    const int MTN = MROWS / 256;  // 40
    layer1_kernel<<<dim3(MROWS / 32, 8), 256, 0, stream>>>(ins, w1, b1, h1lo, h1hi, 5120, 0);
    // ONE L2 GEMM: 1280 tiles (640 long), snake-LPT, band-major
    gemm_spec<<<256, 512, 0, stream>>>(h1lo, h1hi, 5120, W0s2, W2s2, Bc2, nullptr, H2,
                                       8, 16, 2048, 8192, 32 * MTN, 16 * MTN, MTN, 16, 16);
    ln_spec_kernel<<<MROWS, 256, 0, stream>>>(H2, b2, lng, lnb, H2);
    // L3 GEMM over all rows: 320 tiles (160 long)
    gemm_spec<<<256, 512, 0, stream>>>(H2, H2, BIGMS, W0s3, W2s3, Bc3, Z, nullptr,
                                       2, 4, 512, 2048, 8 * MTN, 4 * MTN, MTN, 4, 4);
    out_ep_kernel<<<MROWS * 2, 256, 0, stream>>>(Z, b3, out);
  } else {
    // ---- fallback: chunked flow (persistent-snake GEMMs), no out-scratch ----
    static const int Pcand[8] = {1, 2, 4, 5, 8, 10, 20, 40};
    int P = 40;
    for (int pi = 0; pi < 8; ++pi) {
      size_t mc = (size_t)MROWS / Pcand[pi];
      size_t need = WT_BYTES + mc * 8192 * 2 * 2 + 4096;
      if (need <= ws_size) { P = Pcand[pi]; break; }
    }
    const int Mc = MROWS / P, MTN = Mc / 256;
    unsigned short* h1s = (unsigned short*)chunk_base;                     // Mc x 8192 bf16
    unsigned short* C2  = (unsigned short*)(chunk_base + (size_t)Mc * 8192 * 2);
    float*          Z   = (float*)C2;                                      // Mc x 2048 f32 (alias)
    for (int c = 0; c < P; ++c) {
      int row0 = c * Mc;
      layer1_kernel<<<dim3(Mc / 32, 8), 256, 0, stream>>>(ins, w1, b1, h1s, h1s, BIGMS, row0);
      gemm_spec<<<256, 512, 0, stream>>>(h1s, h1s, BIGMS, W0s2, W2s2, Bc2, nullptr, C2,
                                         8, 16, 2048, 8192, 32 * MTN, 16 * MTN, MTN, 16, 16);
      ln_spec_kernel<<<Mc, 256, 0, stream>>>(C2, b2, lng, lnb, h1s);
      gemm_spec<<<256, 512, 0, stream>>>(h1s, h1s, BIGMS, W0s3, W2s3, Bc3, Z, nullptr,
                                         2, 4, 512, 2048, 8 * MTN, 4 * MTN, MTN, 4, 4);
      out_ep_kernel<<<Mc * 2, 256, 0, stream>>>(Z, b3, out + (size_t)row0 * 2048);
    }
  }
}

// Round 6
// 1018.170 us; speedup vs baseline: 1.0603x; 1.0603x over previous
//
#include <hip/hip_runtime.h>
#include <stdint.h>

// RotEncoderMLP via Z4-spectral (DFT) decomposition of the C4 group convs.
//   x^[0]=x0+x1+x2+x3, x^[2]=x0-x1+x2-x3, x^[1]=ur+i*ui (ur=x0-x2, ui=x3-x1)
//   y^[w] = conj(W^[w]) . x^[w];  y[g] = (1/4)[y^0 + (-1)^g y^2 + 2 Re(y^1 i^g)]
// MACs: 16*HID^2 -> 6*HID^2.
// R7: 256x256 8-phase pipelined GEMM (m201: T2+T3+T4+T5). R8: balanced panels.
// R9: persistent-snake LPT + fused single L3 (duty 60->85%). R10: P8-stage
// slack fix -> 282us/chunk, MfmaUtil 39.7, 990us total (proven baseline).
// R11: FAILED - merged path gated on out_size, which failed at runtime ->
// fallback re-split L3 (2x160 tiles) and band-major order cost 5% (FETCH up).
// R12: merged L2 via d_out-as-scratch enabled UNCONDITIONALLY on ws>=315MB
// (d_out must hold 84MB by problem shape); R10 column-major LPT decode
// restored; A-stage tail offsets wrap k->0 (last d_out row abuts buffer end;
// counts unchanged -> counted-vmcnt ledger intact). Fallback = R10 chunked.

#define HID 2048
#define MROWS 10240

typedef float floatx4 __attribute__((ext_vector_type(4)));
typedef __bf16 bf16x8 __attribute__((ext_vector_type(8)));

__device__ __forceinline__ unsigned short f2bf(float f) {
  union { float f; unsigned int u; } v; v.f = f;
  unsigned int r = v.u + 0x7fffu + ((v.u >> 16) & 1u);  // RNE
  return (unsigned short)(r >> 16);
}
__device__ __forceinline__ float bf2f(unsigned short s) {
  union { unsigned int u; float f; } v; v.u = ((unsigned int)s) << 16;
  return v.f;
}

// ---------- spectral weight transform: w (4,NO,2048) f32 -> W0s, W2s (NO x 2048 bf16),
// Bc (2*NO x 4096 bf16) = [[Vr, -Vi],[Vi, Vr]] ----------
template <int NO>
__global__ __launch_bounds__(256) void wtrans_kernel(const float* __restrict__ w,
                                                     unsigned short* __restrict__ W0s,
                                                     unsigned short* __restrict__ W2s,
                                                     unsigned short* __restrict__ Bc) {
  int idx = blockIdx.x * 256 + threadIdx.x;       // i * 512 + j4
  int i = idx >> 9, j4 = idx & 511;
  const float4* wp = (const float4*)w;
  float4 w0 = wp[0 * NO * 512 + i * 512 + j4];
  float4 w1 = wp[1 * NO * 512 + i * 512 + j4];
  float4 w2 = wp[2 * NO * 512 + i * 512 + j4];
  float4 w3 = wp[3 * NO * 512 + i * 512 + j4];
  ushort4 s0, s2, vr, vi, nvi;
#define DO(c)                                        \
  s0.c = f2bf(w0.c + w1.c + w2.c + w3.c);            \
  s2.c = f2bf(w0.c - w1.c + w2.c - w3.c);            \
  vr.c = f2bf(w0.c - w2.c);                          \
  vi.c = f2bf(w1.c - w3.c);                          \
  nvi.c = f2bf(-(w1.c - w3.c));
  DO(x) DO(y) DO(z) DO(w)
#undef DO
  ((ushort4*)W0s)[i * 512 + j4] = s0;
  ((ushort4*)W2s)[i * 512 + j4] = s2;
  ((ushort4*)Bc)[i * 1024 + j4] = vr;            // row i:    [Vr | -Vi]
  ((ushort4*)Bc)[i * 1024 + 512 + j4] = nvi;
  ((ushort4*)Bc)[(NO + i) * 1024 + j4] = vi;     // row NO+i: [Vi |  Vr]
  ((ushort4*)Bc)[(NO + i) * 1024 + 512 + j4] = vr;
}

// ---------- orbit-stack + layer1 + relu + forward-DFT -> h1 bf16 (rows x 8192: [u0|u2|ur|ui]) ----------
// Output rows (chunk-local orow) split: orow < msplit -> hlo, else hhi.
__global__ __launch_bounds__(256) void layer1_kernel(const float* __restrict__ ins,
                                                     const float* __restrict__ w1,
                                                     const float* __restrict__ b1,
                                                     unsigned short* __restrict__ hlo,
                                                     unsigned short* __restrict__ hhi,
                                                     int msplit, int row0) {
  __shared__ float orbs[32][28];
  int t = threadIdx.x;
  int b0 = blockIdx.x * 32;            // chunk-local
  int i = blockIdx.y * 256 + t;
  if (t < 32) {
    const float* x = ins + (size_t)(row0 + b0 + t) * 25;
    float v[25];
#pragma unroll
    for (int p = 0; p < 25; ++p) v[p] = x[p];
    float* o = orbs[t];
    o[0] = v[12]; o[7] = v[12]; o[14] = v[12]; o[21] = v[12];
#pragma unroll
    for (int r = 0; r < 2; ++r)
#pragma unroll
      for (int c = 0; c < 3; ++c) {
        int m = 1 + r * 3 + c;
        o[m]      = v[r * 5 + c];
        o[7 + m]  = v[c * 5 + (4 - r)];
        o[14 + m] = v[(4 - r) * 5 + (4 - c)];
        o[21 + m] = v[(4 - c) * 5 + r];
      }
  }
  __syncthreads();
  float w[4][7];
#pragma unroll
  for (int r = 0; r < 4; ++r)
#pragma unroll
    for (int j = 0; j < 7; ++j) w[r][j] = w1[(r * HID + i) * 7 + j];
  float bias = b1[i];
  for (int s = 0; s < 32; ++s) {
    float a[4] = {bias, bias, bias, bias};
#pragma unroll
    for (int hh = 0; hh < 4; ++hh)
#pragma unroll
      for (int j = 0; j < 7; ++j) {
        float ov = orbs[s][hh * 7 + j];
#pragma unroll
        for (int g = 0; g < 4; ++g) a[g] += w[(hh - g) & 3][j] * ov;
      }
    float h0 = fmaxf(a[0], 0.f), h1 = fmaxf(a[1], 0.f);
    float h2 = fmaxf(a[2], 0.f), h3 = fmaxf(a[3], 0.f);
    int orow = b0 + s;
    unsigned short* hp = (orow < msplit) ? hlo + (size_t)orow * 8192
                                         : hhi + (size_t)(orow - msplit) * 8192;
    hp[i]        = f2bf(h0 + h1 + h2 + h3);  // u0
    hp[2048 + i] = f2bf(h0 - h1 + h2 - h3);  // u2
    hp[4096 + i] = f2bf(h0 - h2);            // ur
    hp[6144 + i] = f2bf(h3 - h1);            // ui
  }
}

// ---------- persistent 256x256 8-phase pipelined bf16 MFMA GEMM ----------
// Work list (LPT, column-major as measured in R10): tiles [0,NTL) = long-K
// (nt = s2 + wt/MTN, mt = wt%MTN), [NTL,NT) = short-K (nt = (wt-NTL)/MTN).
// G blocks snake: pass p -> tile p*G+b (even) / (p+1)*G-1-b (odd).
// A rows split: m0 < MS -> Alo else Ahi (merged path: hi half lives in d_out).
// n-tile routing: nt<s1: B0,K=2048,aoff=0; nt<s2: B1,K=2048,aoff=2048; else B2,K=4096,aoff=4096.
// Output: bf16 to Cb (if non-null) else f32 to Cf.
// LDS: row remap (half-tile = 2 contiguous 64-row global_load_lds sweeps);
// chunk swizzle ch ^= (lrow&7), source pre-swizzled, read ch = c ^ (lane15&7).
// Stage ring: P2:A0mh0 P3:B0nh0 P4:B0nh1 P5:A0mh1 P6:A1mh0 P7:B1nh0
// P8:B1nh1+A1mh1; counted vmcnt(6) at P4/P8 only. A-stage tail offsets wrap
// k->0 (garbage, never consumed; count unchanged; avoids reads past d_out
// end on the last Ahi row). B stages unwrapped (ws-interior, safe).

__global__ __launch_bounds__(512, 2) void gemm_spec(const unsigned short* __restrict__ Alo,
                                                    const unsigned short* __restrict__ Ahi,
                                                    int MS,
                                                    const unsigned short* __restrict__ B0,
                                                    const unsigned short* __restrict__ B1,
                                                    const unsigned short* __restrict__ B2,
                                                    float* __restrict__ Cf,
                                                    unsigned short* __restrict__ Cb,
                                                    int s1, int s2, int N0, int ldc,
                                                    int NT, int NTL, int MTN) {
  __shared__ __align__(16) unsigned short As[2][16384];
  __shared__ __align__(16) unsigned short Bs[2][16384];
  int tid = threadIdx.x;
  int wave = tid >> 6, lane = tid & 63;
  int lane15 = lane & 15, lane4 = lane >> 4, l7 = lane15 & 7;
  int wm = wave >> 2, wn = wave & 3;
  int wm64 = wm << 6, wn32 = wn << 5;

  int srow = tid >> 3;                               // 0..63 within a sweep
  int scol = ((tid & 7) ^ ((tid >> 3) & 7)) << 3;    // pre-swizzled source chunk
  int bs64 = (srow >> 5) << 6;                       // 0 or 64 (wave-uniform)

#define STA(buf, mh, kk)                                                                              \
  __builtin_amdgcn_global_load_lds(                                                                   \
      (const __attribute__((address_space(1))) void*)(Agb + (size_t)((mh) * 64) * 8192 + (kk)),       \
      (__attribute__((address_space(3))) void*)((char*)As[buf] + (mh) * 16384 + wave * 1024),         \
      16, 0, 0);                                                                                      \
  __builtin_amdgcn_global_load_lds(                                                                   \
      (const __attribute__((address_space(1))) void*)(Agb + (size_t)((mh) * 64 + 128) * 8192 + (kk)), \
      (__attribute__((address_space(3))) void*)((char*)As[buf] + (mh) * 16384 + 8192 + wave * 1024),  \
      16, 0, 0)

#define STB(buf, nh, kk)                                                                              \
  __builtin_amdgcn_global_load_lds(                                                                   \
      (const __attribute__((address_space(1))) void*)(Bgb + (size_t)(bs64 + (nh) * 32) * ldb + (kk)), \
      (__attribute__((address_space(3))) void*)((char*)Bs[buf] + (nh) * 16384 + wave * 1024),         \
      16, 0, 0);                                                                                      \
  __builtin_amdgcn_global_load_lds(                                                                   \
      (const __attribute__((address_space(1))) void*)(Bgb + (size_t)(bs64 + 128 + (nh) * 32) * ldb + (kk)), \
      (__attribute__((address_space(3))) void*)((char*)Bs[buf] + (nh) * 16384 + 8192 + wave * 1024),  \
      16, 0, 0)

#define RAF(buf, mh)                                                                                  \
  _Pragma("unroll") for (int mi_ = 0; mi_ < 4; ++mi_)                                                 \
  _Pragma("unroll") for (int ks_ = 0; ks_ < 2; ++ks_)                                                 \
      af[mi_][ks_] = *(const bf16x8*)((const char*)As[buf] +                                          \
          (((mh) * 128 + wm64 + mi_ * 16 + lane15) << 7) + (((ks_ * 4 + lane4) ^ l7) << 4))

#define RBF(dst, buf, nh)                                                                             \
  _Pragma("unroll") for (int ni_ = 0; ni_ < 2; ++ni_)                                                 \
  _Pragma("unroll") for (int ks_ = 0; ks_ < 2; ++ks_)                                                 \
      dst[ni_][ks_] = *(const bf16x8*)((const char*)Bs[buf] +                                         \
          (((nh) * 128 + wn32 + ni_ * 16 + lane15) << 7) + (((ks_ * 4 + lane4) ^ l7) << 4))

#define MM(mh, nh, bF)                                                                                \
  _Pragma("unroll") for (int mi_ = 0; mi_ < 4; ++mi_)                                                 \
  _Pragma("unroll") for (int ni_ = 0; ni_ < 2; ++ni_)                                                 \
  _Pragma("unroll") for (int ks_ = 0; ks_ < 2; ++ks_)                                                 \
      acc[(mh) * 4 + mi_][(nh) * 2 + ni_] = __builtin_amdgcn_mfma_f32_16x16x32_bf16(                  \
          af[mi_][ks_], bF[ni_][ks_], acc[(mh) * 4 + mi_][(nh) * 2 + ni_], 0, 0, 0)

#define BAR() __builtin_amdgcn_s_barrier()
#define LGKM0() asm volatile("s_waitcnt lgkmcnt(0)" ::: "memory")
#define LGKM8() asm volatile("s_waitcnt lgkmcnt(8)" ::: "memory")
#define VM6() asm volatile("s_waitcnt vmcnt(6)" ::: "memory")
#define VM8() asm volatile("s_waitcnt vmcnt(8)" ::: "memory")

  bf16x8 af[4][2], b0r[2][2], b1r[2][2];
  const floatx4 fz = {0.f, 0.f, 0.f, 0.f};
  floatx4 acc[8][4];

  int G = (int)gridDim.x;
  for (int pass = 0;; ++pass) {
    int base = pass * G;
    if (base >= NT) break;
    int wt = (pass & 1) ? (base + G - 1 - (int)blockIdx.x) : (base + (int)blockIdx.x);
    if (wt >= NT) continue;

    // column-major LPT decode (R10-measured)
    int mt, nt;
    if (wt < NTL) { int j = wt / MTN; nt = s2 + j; mt = wt - j * MTN; }
    else          { int w2_ = wt - NTL; int j = w2_ / MTN; nt = j; mt = w2_ - j * MTN; }
    int m0 = mt * 256;

    const unsigned short* Bp;
    int K, aoff, coff, nloc;
    if (nt < s1)      { Bp = B0; K = 2048; aoff = 0;    coff = 0;      nloc = nt * 256; }
    else if (nt < s2) { Bp = B1; K = 2048; aoff = 2048; coff = N0;     nloc = (nt - s1) * 256; }
    else              { Bp = B2; K = 4096; aoff = 4096; coff = 2 * N0; nloc = (nt - s2) * 256; }
    int ldb = K;

    const unsigned short* Ab = (m0 < MS) ? (Alo + (size_t)m0 * 8192)
                                         : (Ahi + (size_t)(m0 - MS) * 8192);
    const unsigned short* Agb = Ab + (size_t)srow * 8192 + aoff + scol;
    const unsigned short* Bgb = Bp + (size_t)(nloc + (srow & 31)) * ldb + scol;

#pragma unroll
    for (int a = 0; a < 8; ++a)
#pragma unroll
      for (int b = 0; b < 4; ++b) acc[a][b] = fz;

    // Prologue: T0 (buf0,k=0) then T1 (buf1,k=64), all 16 loads; vmcnt(8)
    // retires exactly T0's 8 (drains prev epilogue stores first, FIFO).
    STA(0, 0, 0); STB(0, 0, 0); STB(0, 1, 0); STA(0, 1, 0);
    STA(1, 0, 64); STB(1, 0, 64); STB(1, 1, 64); STA(1, 1, 64);
    VM8();
    BAR();

    for (int k0 = 0; k0 < K; k0 += 128) {
      int ka = k0 + 128; if (ka >= K) ka = 0;   // A-stage tail wrap (last iter
      int kb = k0 + 192; if (kb >= K) kb = 0;   // only): garbage, never consumed
      // ---- P1: quad(0,0) of tile A (buf0)
      RAF(0, 0); RBF(b0r, 0, 0);
      LGKM8();
      BAR(); LGKM0();
      __builtin_amdgcn_s_setprio(1); MM(0, 0, b0r); __builtin_amdgcn_s_setprio(0);
      BAR();
      // ---- P2: quad(0,1); stage Ta'.A-mh0 (buf0, freed P1)
      RBF(b1r, 0, 1);
      STA(0, 0, ka);
      BAR(); LGKM0();
      __builtin_amdgcn_s_setprio(1); MM(0, 1, b1r); __builtin_amdgcn_s_setprio(0);
      BAR();
      // ---- P3: quad(1,0); stage Ta'.B-nh0 (freed P1)
      RAF(0, 1);
      STB(0, 0, k0 + 128);
      BAR(); LGKM0();
      __builtin_amdgcn_s_setprio(1); MM(1, 0, b0r); __builtin_amdgcn_s_setprio(0);
      BAR();
      // ---- P4: quad(1,1); stage Ta'.B-nh1 (freed P2); counted vmcnt
      // outstanding: prevP7(2)+prevP8(4)+P2..P4(6)=12 -> retire prevP7+prevP8
      STB(0, 1, k0 + 128);
      BAR(); LGKM0();
      __builtin_amdgcn_s_setprio(1); MM(1, 1, b1r); __builtin_amdgcn_s_setprio(0);
      VM6();
      BAR();
      // ---- P5: tile B (buf1) quad(0,0); stage Ta'.A-mh1 (freed P3)
      RAF(1, 0); RBF(b0r, 1, 0);
      STA(0, 1, ka);
      LGKM8();
      BAR(); LGKM0();
      __builtin_amdgcn_s_setprio(1); MM(0, 0, b0r); __builtin_amdgcn_s_setprio(0);
      BAR();
      // ---- P6: quad(0,1); stage Tb'.A-mh0 (buf1, freed P5)
      RBF(b1r, 1, 1);
      STA(1, 0, kb);
      BAR(); LGKM0();
      __builtin_amdgcn_s_setprio(1); MM(0, 1, b1r); __builtin_amdgcn_s_setprio(0);
      BAR();
      // ---- P7: quad(1,0); stage Tb'.B-nh0 (freed P5)
      RAF(1, 1);
      STB(1, 0, k0 + 192);
      BAR(); LGKM0();
      __builtin_amdgcn_s_setprio(1); MM(1, 0, b0r); __builtin_amdgcn_s_setprio(0);
      BAR();
      // ---- P8: quad(1,1); stage Tb'.B-nh1 (freed P6) + Tb'.A-mh1 (freed P7);
      // counted vmcnt: outstanding P5..P8(10) -> retire P5+P6
      STB(1, 1, k0 + 192);
      STA(1, 1, kb);
      BAR(); LGKM0();
      __builtin_amdgcn_s_setprio(1); MM(1, 1, b1r); __builtin_amdgcn_s_setprio(0);
      VM6();
      BAR();
    }
    asm volatile("s_waitcnt vmcnt(0)" ::: "memory");

    // epilogue: C/D layout col=lane&15, row=(lane>>4)*4+r
#pragma unroll
    for (int ni = 0; ni < 4; ++ni) {
      int col = coff + nloc + wn * 64 + (ni >> 1) * 32 + (ni & 1) * 16 + lane15;
#pragma unroll
      for (int mi = 0; mi < 8; ++mi) {
        int row = m0 + wm * 128 + (mi >> 2) * 64 + (mi & 3) * 16 + lane4 * 4;
        if (Cb) {
#pragma unroll
          for (int r = 0; r < 4; ++r)
            Cb[(size_t)(row + r) * ldc + col] = f2bf(acc[mi][ni][r]);
        } else {
#pragma unroll
          for (int r = 0; r < 4; ++r)
            Cf[(size_t)(row + r) * ldc + col] = acc[mi][ni][r];
        }
      }
    }
  }
#undef STA
#undef STB
#undef RAF
#undef RBF
#undef MM
#undef BAR
#undef LGKM0
#undef LGKM8
#undef VM6
#undef VM8
}

// ---------- inverse-DFT (+b2, /4) -> 4x LayerNorm -> relu -> forward-DFT -> out bf16 ----------
// NOTE: may be called with h1s == C2 (in-place): each row is fully register-
// resident between read and write (reads all precede the reduction barrier).
__global__ __launch_bounds__(256) void ln_spec_kernel(const unsigned short* C2,
                                                      const float* __restrict__ b2,
                                                      const float* __restrict__ ln_g,
                                                      const float* __restrict__ ln_b,
                                                      unsigned short* h1s) {
  int t = threadIdx.x;
  size_t base = (size_t)blockIdx.x * 8192;
  const ushort4* p = (const ushort4*)(C2 + base);   // planes: v0|v2|vr|vi (512 ushort4 each)
  const float4* bp2 = (const float4*)b2;
  float4 y[4][2];
  float s[4] = {0, 0, 0, 0}, q[4] = {0, 0, 0, 0};
#pragma unroll
  for (int hl = 0; hl < 2; ++hl) {
    int j = hl * 256 + t;
    ushort4 u0 = p[j], u2 = p[512 + j], ur = p[1024 + j], ui = p[1536 + j];
    float4 bb = bp2[j];
#define DO(c)                                                   \
  {                                                             \
    float v0 = bf2f(u0.c), v2 = bf2f(u2.c);                     \
    float vr = bf2f(ur.c), vi = bf2f(ui.c);                     \
    float e0 = 0.25f * (v0 + v2 + 2.f * vr) + bb.c;             \
    float e1 = 0.25f * (v0 - v2 - 2.f * vi) + bb.c;             \
    float e2 = 0.25f * (v0 + v2 - 2.f * vr) + bb.c;             \
    float e3 = 0.25f * (v0 - v2 + 2.f * vi) + bb.c;             \
    y[0][hl].c = e0; y[1][hl].c = e1; y[2][hl].c = e2; y[3][hl].c = e3; \
    s[0] += e0; q[0] += e0 * e0; s[1] += e1; q[1] += e1 * e1;   \
    s[2] += e2; q[2] += e2 * e2; s[3] += e3; q[3] += e3 * e3;   \
  }
    DO(x) DO(y) DO(z) DO(w)
#undef DO
  }
#pragma unroll
  for (int off = 32; off > 0; off >>= 1)
#pragma unroll
    for (int g = 0; g < 4; ++g) {
      s[g] += __shfl_down(s[g], off, 64);
      q[g] += __shfl_down(q[g], off, 64);
    }
  __shared__ float rs[4][4], rq[4][4];
  int w = t >> 6, l = t & 63;
  if (l == 0)
#pragma unroll
    for (int g = 0; g < 4; ++g) { rs[w][g] = s[g]; rq[w][g] = q[g]; }
  __syncthreads();
  float mean[4], rstd[4];
#pragma unroll
  for (int g = 0; g < 4; ++g) {
    float ss = rs[0][g] + rs[1][g] + rs[2][g] + rs[3][g];
    float qq = rq[0][g] + rq[1][g] + rq[2][g] + rq[3][g];
    mean[g] = ss * (1.f / HID);
    float var = qq * (1.f / HID) - mean[g] * mean[g];
    rstd[g] = rsqrtf(var + 1e-5f);
  }
  const float4* gp = (const float4*)ln_g;
  const float4* lbp = (const float4*)ln_b;
#pragma unroll
  for (int hl = 0; hl < 2; ++hl) {
    int j = hl * 256 + t;
    float4 gg = gp[j], lb = lbp[j];
    ushort4 o[4];
#define DO(c)                                                               \
  {                                                                         \
    float h0 = fmaxf((y[0][hl].c - mean[0]) * rstd[0] * gg.c + lb.c, 0.f);  \
    float h1 = fmaxf((y[1][hl].c - mean[1]) * rstd[1] * gg.c + lb.c, 0.f);  \
    float h2 = fmaxf((y[2][hl].c - mean[2]) * rstd[2] * gg.c + lb.c, 0.f);  \
    float h3 = fmaxf((y[3][hl].c - mean[3]) * rstd[3] * gg.c + lb.c, 0.f);  \
    o[0].c = f2bf(h0 + h1 + h2 + h3);                                       \
    o[1].c = f2bf(h0 - h1 + h2 - h3);                                       \
    o[2].c = f2bf(h0 - h2);                                                 \
    o[3].c = f2bf(h3 - h1);                                                 \
  }
    DO(x) DO(y) DO(z) DO(w)
#undef DO
    size_t ob = (size_t)blockIdx.x * 8192;
#pragma unroll
    for (int pl = 0; pl < 4; ++pl)
      ((ushort4*)(h1s + ob + pl * 2048))[j] = o[pl];
  }
}

// ---------- final inverse-DFT (+b3, /4): Z (rows x 2048 f32 [z0|z2|zr|zi]) -> out ----------
__global__ __launch_bounds__(256) void out_ep_kernel(const float* __restrict__ Z,
                                                     const float* __restrict__ b3,
                                                     float* __restrict__ out) {
  int e = blockIdx.x * 256 + threadIdx.x;
  int row = e >> 9, i = e & 511;
  size_t base = (size_t)row * 2048;
  float z0 = Z[base + i], z2 = Z[base + 512 + i];
  float zr = Z[base + 1024 + i], zi = Z[base + 1536 + i];
  float bv = b3[i];
  out[base + i]        = 0.25f * (z0 + z2 + 2.f * zr) + bv;
  out[base + 512 + i]  = 0.25f * (z0 - z2 - 2.f * zi) + bv;
  out[base + 1024 + i] = 0.25f * (z0 + z2 - 2.f * zr) + bv;
  out[base + 1536 + i] = 0.25f * (z0 - z2 + 2.f * zi) + bv;
}

extern "C" void kernel_launch(void* const* d_in, const int* in_sizes, int n_in,
                              void* d_out, int out_size, void* d_ws, size_t ws_size,
                              hipStream_t stream) {
  const float* ins = (const float*)d_in[0];
  const float* w1  = (const float*)d_in[1];
  const float* b1  = (const float*)d_in[2];
  const float* w2  = (const float*)d_in[3];
  const float* b2  = (const float*)d_in[4];
  const float* w3  = (const float*)d_in[5];
  const float* b3  = (const float*)d_in[6];
  const float* lng = (const float*)d_in[7];
  const float* lnb = (const float*)d_in[8];
  float* out = (float*)d_out;
  char* ws = (char*)d_ws;
  const int BIGMS = 0x40000000;

  // Spectral weights (bf16), persistent at base of ws.
  unsigned short* W0s2 = (unsigned short*)ws;
  unsigned short* W2s2 = W0s2 + 4194304;
  unsigned short* Bc2  = W2s2 + 4194304;
  unsigned short* W0s3 = Bc2 + 16777216;
  unsigned short* W2s3 = W0s3 + 1048576;
  unsigned short* Bc3  = W2s3 + 1048576;
  const size_t WT_BYTES = 62914560ull;
  char* chunk_base = ws + WT_BYTES;

  wtrans_kernel<2048><<<4096, 256, 0, stream>>>(w2, W0s2, W2s2, Bc2);
  wtrans_kernel<512><<<1024, 256, 0, stream>>>(w3, W0s3, W2s3, Bc3);

  const size_t H1L_BYTES = (size_t)5120 * 8192 * 2;     // 84 MB: rows 0..5119 (Z f32 full aliases this)
  const size_t H2_BYTES  = (size_t)MROWS * 8192 * 2;    // 168 MB
  const size_t need_merged = WT_BYTES + H1L_BYTES + H2_BYTES + 4096;  // 315 MB (R9-proven budget)

  if (ws_size >= need_merged) {
    // ---- merged path: full-rows h1s split (lo in ws, hi in d_out).
    // d_out holds 10240x2048 f32 = 84 MB by problem shape; it is dead as
    // output until out_ep fully overwrites it at the end.
    unsigned short* h1lo = (unsigned short*)chunk_base;               // rows 0..5119
    unsigned short* h1hi = (unsigned short*)out;                      // rows 5120..10239
    float*          Z    = (float*)chunk_base;                        // 10240 x 2048 f32 (alias h1lo)
    unsigned short* H2   = (unsigned short*)(chunk_base + H1L_BYTES); // 10240 x 8192 bf16
    const int MTN = MROWS / 256;  // 40
    layer1_kernel<<<dim3(MROWS / 32, 8), 256, 0, stream>>>(ins, w1, b1, h1lo, h1hi, 5120, 0);
    // ONE L2 GEMM: 1280 tiles (640 long), snake-LPT column-major
    gemm_spec<<<256, 512, 0, stream>>>(h1lo, h1hi, 5120, W0s2, W2s2, Bc2, nullptr, H2,
                                       8, 16, 2048, 8192, 32 * MTN, 16 * MTN, MTN);
    ln_spec_kernel<<<MROWS, 256, 0, stream>>>(H2, b2, lng, lnb, H2);
    // ONE L3 GEMM over all rows: 320 tiles (160 long)
    gemm_spec<<<256, 512, 0, stream>>>(H2, H2, BIGMS, W0s3, W2s3, Bc3, Z, nullptr,
                                       2, 4, 512, 2048, 8 * MTN, 4 * MTN, MTN);
    out_ep_kernel<<<MROWS * 2, 256, 0, stream>>>(Z, b3, out);
  } else {
    // ---- fallback: R10 chunked flow (persistent-snake GEMMs) ----
    static const int Pcand[8] = {1, 2, 4, 5, 8, 10, 20, 40};
    int P = 40;
    for (int pi = 0; pi < 8; ++pi) {
      size_t mc = (size_t)MROWS / Pcand[pi];
      size_t need = WT_BYTES + mc * 8192 * 2 * 2 + 4096;
      if (need <= ws_size) { P = Pcand[pi]; break; }
    }
    const int Mc = MROWS / P, MTN = Mc / 256;
    unsigned short* h1s = (unsigned short*)chunk_base;                     // Mc x 8192 bf16
    unsigned short* C2  = (unsigned short*)(chunk_base + (size_t)Mc * 8192 * 2);
    float*          Z   = (float*)C2;                                      // Mc x 2048 f32 (alias)
    for (int c = 0; c < P; ++c) {
      int row0 = c * Mc;
      layer1_kernel<<<dim3(Mc / 32, 8), 256, 0, stream>>>(ins, w1, b1, h1s, h1s, BIGMS, row0);
      gemm_spec<<<256, 512, 0, stream>>>(h1s, h1s, BIGMS, W0s2, W2s2, Bc2, nullptr, C2,
                                         8, 16, 2048, 8192, 32 * MTN, 16 * MTN, MTN);
      ln_spec_kernel<<<Mc, 256, 0, stream>>>(C2, b2, lng, lnb, h1s);
      gemm_spec<<<256, 512, 0, stream>>>(h1s, h1s, BIGMS, W0s3, W2s3, Bc3, Z, nullptr,
                                         2, 4, 512, 2048, 8 * MTN, 4 * MTN, MTN);
      out_ep_kernel<<<Mc * 2, 256, 0, stream>>>(Z, b3, out + (size_t)row0 * 2048);
    }
  }
}